// Round 10
// baseline (132.568 us; speedup 1.0000x reference)
//
#include <hip/hip_runtime.h>

constexpr int N_     = 2048;
constexpr int IN_DIM = 512;
constexpr int HID    = 512;
constexpr int EMB    = 256;
constexpr int M_     = 256;

typedef __attribute__((ext_vector_type(8))) short short8;
typedef __attribute__((ext_vector_type(4))) float f32x4;
typedef __attribute__((ext_vector_type(2))) _Float16 h2v;

#if defined(__has_builtin)
#if __has_builtin(__builtin_amdgcn_fdot2)
#define HAVE_FDOT2 1
#endif
#endif

union U32H2 { unsigned int u; h2v v; };
union S8U   { short8 s; unsigned short us[8]; };

__device__ __forceinline__ unsigned short f2bf(float f) {
    union { float f; unsigned int u; } v; v.f = f;
    return (unsigned short)((v.u + 0x7fffu + ((v.u >> 16) & 1u)) >> 16);
}
__device__ __forceinline__ unsigned int packh2(float a, float b) {
    U32H2 r; r.v[0] = (_Float16)a; r.v[1] = (_Float16)b; return r.u;
}
__device__ __forceinline__ h2v relu2(h2v s) {
#if defined(__has_builtin) && __has_builtin(__builtin_elementwise_max)
    U32H2 z; z.u = 0u;
    return __builtin_elementwise_max(s, z.v);
#else
    U32H2 t; t.v = s;
    const unsigned int m = ((t.u & 0x80000000u) ? 0xFFFF0000u : 0u) |
                           ((t.u & 0x00008000u) ? 0x0000FFFFu : 0u);
    t.u &= ~m;
    return t.v;
#endif
}
__device__ __forceinline__ short8 cvt8(const float4& f0, const float4& f1) {
    S8U t;
    t.us[0] = f2bf(f0.x); t.us[1] = f2bf(f0.y);
    t.us[2] = f2bf(f0.z); t.us[3] = f2bf(f0.w);
    t.us[4] = f2bf(f1.x); t.us[5] = f2bf(f1.y);
    t.us[6] = f2bf(f1.z); t.us[7] = f2bf(f1.w);
    return t.s;
}

// ---------------------------------------------------------------------------
// bf16-MFMA NT GEMM with inline fp32->bf16 conversion in staging.
// C[r,c] = relu( sum_k A[r,k]*W[c,k] + bias[c] ), bf16 out.
// A: fp32 if ACVT else bf16; W: always fp32 (converted during staging).
// BK=128, double-buffered LDS, 4 waves (2x2 subtiles).
// ---------------------------------------------------------------------------
template<int BM, int BN, bool ACVT>
__global__ __launch_bounds__(256, 2)
void gemm_cvt(const void* __restrict__ Ap, int lda,
              const float* __restrict__ Wf, int ldw,
              const float* __restrict__ bias,
              unsigned short* __restrict__ Cout, int ldc, int K)
{
    constexpr int BK = 128, LDK = BK + 8;
    constexpr int SM = BM / 2, SN = BN / 2;
    constexpr int FM = SM / 16, FN = SN / 16;
    constexpr int AIT = BM / 16, WIT = BN / 16;
    __shared__ unsigned short As[2][BM][LDK];
    __shared__ unsigned short Bs[2][BN][LDK];

    const int tid  = threadIdx.x;
    const int row0 = blockIdx.x * BM, col0 = blockIdx.y * BN;
    const int wv = tid >> 6, lane = tid & 63;
    const int wr = wv >> 1, wc = wv & 1;
    const int lr = lane & 15, lq = lane >> 4;

    f32x4 acc[FM][FN];
#pragma unroll
    for (int i = 0; i < FM; ++i)
#pragma unroll
        for (int j = 0; j < FN; ++j) acc[i][j] = (f32x4)0.f;

    float4 paf[AIT][2];
    short8 pab[AIT];
    float4 pwf[WIT][2];

    auto issue = [&](int k0) {
#pragma unroll
        for (int i = 0; i < AIT; ++i) {
            const int idx = tid + i * 256, r = idx >> 4, c8 = idx & 15;
            if (ACVT) {
                const float* A = (const float*)Ap;
                paf[i][0] = *(const float4*)&A[(size_t)(row0 + r) * lda + k0 + c8 * 8];
                paf[i][1] = *(const float4*)&A[(size_t)(row0 + r) * lda + k0 + c8 * 8 + 4];
            } else {
                const unsigned short* A = (const unsigned short*)Ap;
                pab[i] = *(const short8*)&A[(size_t)(row0 + r) * lda + k0 + c8 * 8];
            }
        }
#pragma unroll
        for (int i = 0; i < WIT; ++i) {
            const int idx = tid + i * 256, r = idx >> 4, c8 = idx & 15;
            pwf[i][0] = *(const float4*)&Wf[(size_t)(col0 + r) * ldw + k0 + c8 * 8];
            pwf[i][1] = *(const float4*)&Wf[(size_t)(col0 + r) * ldw + k0 + c8 * 8 + 4];
        }
    };
    auto store = [&](int bsel) {
#pragma unroll
        for (int i = 0; i < AIT; ++i) {
            const int idx = tid + i * 256, r = idx >> 4, c8 = idx & 15;
            *(short8*)&As[bsel][r][c8 * 8] = ACVT ? cvt8(paf[i][0], paf[i][1]) : pab[i];
        }
#pragma unroll
        for (int i = 0; i < WIT; ++i) {
            const int idx = tid + i * 256, r = idx >> 4, c8 = idx & 15;
            *(short8*)&Bs[bsel][r][c8 * 8] = cvt8(pwf[i][0], pwf[i][1]);
        }
    };

    issue(0); store(0);
    const int NC = K / BK;
    for (int c = 0; c < NC; ++c) {
        const int buf = c & 1;
        __syncthreads();
        if (c + 1 < NC) issue((c + 1) * BK);
#pragma unroll
        for (int ks = 0; ks < BK / 32; ++ks) {
            short8 af[FM], bfr[FN];
#pragma unroll
            for (int i = 0; i < FM; ++i)
                af[i] = *(const short8*)&As[buf][wr * SM + i * 16 + lr][ks * 32 + lq * 8];
#pragma unroll
            for (int j = 0; j < FN; ++j)
                bfr[j] = *(const short8*)&Bs[buf][wc * SN + j * 16 + lr][ks * 32 + lq * 8];
#pragma unroll
            for (int i = 0; i < FM; ++i)
#pragma unroll
                for (int j = 0; j < FN; ++j)
                    acc[i][j] = __builtin_amdgcn_mfma_f32_16x16x32_bf16(
                        af[i], bfr[j], acc[i][j], 0, 0, 0);
        }
        if (c + 1 < NC) store((c + 1) & 1);
    }

#pragma unroll
    for (int i = 0; i < FM; ++i) {
#pragma unroll
        for (int j = 0; j < FN; ++j) {
            const int colb = col0 + wc * SN + j * 16 + lr;
#pragma unroll
            for (int e = 0; e < 4; ++e) {
                const int row = row0 + wr * SM + i * 16 + lq * 4 + e;
                float v = fmaxf(acc[i][j][e] + bias[colb], 0.f);
                Cout[(size_t)row * ldc + colb] = f2bf(v);
            }
        }
    }
}

// ---------------------------------------------------------------------------
// Dual GEMM for hxT/cmT (f16 h-pair-packed out), BK=128 double-buffered.
// A = W1 fp32 (strided cols, converted inline).
// blockIdx.y < 32 -> hxT (B = x_emb bf16); >= 32 -> cmT (B = gathered t_emb
// from Ep/Ef/Er fp32, summed + converted inline; +b1 row bias).
// ---------------------------------------------------------------------------
__global__ __launch_bounds__(256, 2)
void gemm_pair(const float* __restrict__ W1,
               const unsigned short* __restrict__ x_emb_bf,
               const int* __restrict__ tuples,
               const float* __restrict__ Ep, const float* __restrict__ Ef,
               const float* __restrict__ Er, const float* __restrict__ b1,
               unsigned int* __restrict__ hxT_p,
               unsigned int* __restrict__ cmT_p)
{
    constexpr int BM = 32, BN = 64, BK = 128, LDK = BK + 8;
    constexpr int SM = 16, SN = 32, FN = 2;
    __shared__ unsigned short As[2][BM][LDK];
    __shared__ unsigned short Bs[2][BN][LDK];

    const int tid = threadIdx.x;
    const bool gat = (blockIdx.y >= 32);
    const int col0 = (gat ? (int)blockIdx.y - 32 : (int)blockIdx.y) * BN;
    const int ldc  = gat ? M_ : N_;
    unsigned int* outp = gat ? cmT_p : hxT_p;
    const int xoff = gat ? EMB : 0;
    const int row0 = blockIdx.x * BM;
    const int K = EMB;   // 256 -> NC = 2

    const int wv = tid >> 6, lane = tid & 63;
    const int wr = wv >> 1, wc = wv & 1;
    const int lr = lane & 15, lq = lane >> 4;

    f32x4 acc[FN];
#pragma unroll
    for (int j = 0; j < FN; ++j) acc[j] = (f32x4)0.f;

    float4 paf[2][2];
    short8 pb[4];
    float4 pbf[4][2];

    auto issue = [&](int k0) {
#pragma unroll
        for (int i = 0; i < 2; ++i) {
            const int idx = tid + i * 256, r = idx >> 4, c8 = idx & 15;
            const size_t base = (size_t)(row0 + r) * (2 * EMB) + xoff + k0 + c8 * 8;
            paf[i][0] = *(const float4*)&W1[base];
            paf[i][1] = *(const float4*)&W1[base + 4];
        }
#pragma unroll
        for (int i = 0; i < 4; ++i) {
            const int idx = tid + i * 256, r = idx >> 4, c8 = idx & 15;
            if (!gat) {
                pb[i] = *(const short8*)&x_emb_bf[(size_t)(col0 + r) * EMB + k0 + c8 * 8];
            } else {
                const int mr = col0 + r;
                const int t0 = tuples[mr * 3 + 0];
                const int t1 = tuples[mr * 3 + 1];
                const int t2 = tuples[mr * 3 + 2];
                const int base = k0 + c8 * 8;
                const float4 a0 = *(const float4*)&Ep[t0 * EMB + base];
                const float4 a1 = *(const float4*)&Ep[t0 * EMB + base + 4];
                const float4 b0 = *(const float4*)&Ef[t1 * EMB + base];
                const float4 b1v = *(const float4*)&Ef[t1 * EMB + base + 4];
                const float4 c0 = *(const float4*)&Er[t2 * EMB + base];
                const float4 c1 = *(const float4*)&Er[t2 * EMB + base + 4];
                pbf[i][0].x = a0.x + b0.x + c0.x;  pbf[i][0].y = a0.y + b0.y + c0.y;
                pbf[i][0].z = a0.z + b0.z + c0.z;  pbf[i][0].w = a0.w + b0.w + c0.w;
                pbf[i][1].x = a1.x + b1v.x + c1.x; pbf[i][1].y = a1.y + b1v.y + c1.y;
                pbf[i][1].z = a1.z + b1v.z + c1.z; pbf[i][1].w = a1.w + b1v.w + c1.w;
            }
        }
    };
    auto store = [&](int bsel) {
#pragma unroll
        for (int i = 0; i < 2; ++i) {
            const int idx = tid + i * 256, r = idx >> 4, c8 = idx & 15;
            *(short8*)&As[bsel][r][c8 * 8] = cvt8(paf[i][0], paf[i][1]);
        }
#pragma unroll
        for (int i = 0; i < 4; ++i) {
            const int idx = tid + i * 256, r = idx >> 4, c8 = idx & 15;
            *(short8*)&Bs[bsel][r][c8 * 8] = gat ? cvt8(pbf[i][0], pbf[i][1]) : pb[i];
        }
    };

    issue(0); store(0);
    const int NC = K / BK;  // 2
    for (int c = 0; c < NC; ++c) {
        const int buf = c & 1;
        __syncthreads();
        if (c + 1 < NC) issue((c + 1) * BK);
#pragma unroll
        for (int ks = 0; ks < BK / 32; ++ks) {
            short8 af, bfr[FN];
            af = *(const short8*)&As[buf][wr * SM + lr][ks * 32 + lq * 8];
#pragma unroll
            for (int j = 0; j < FN; ++j)
                bfr[j] = *(const short8*)&Bs[buf][wc * SN + j * 16 + lr][ks * 32 + lq * 8];
#pragma unroll
            for (int j = 0; j < FN; ++j)
                acc[j] = __builtin_amdgcn_mfma_f32_16x16x32_bf16(af, bfr[j], acc[j], 0, 0, 0);
        }
        if (c + 1 < NC) store((c + 1) & 1);
    }

    const int rowb = row0 + wr * SM + lq * 4;   // multiple of 4 (h index)
#pragma unroll
    for (int j = 0; j < FN; ++j) {
        const int colb = col0 + wc * SN + j * 16 + lr;
#pragma unroll
        for (int e2 = 0; e2 < 2; ++e2) {
            float v0 = acc[j][2 * e2], v1 = acc[j][2 * e2 + 1];
            if (gat) { v0 += b1[rowb + 2 * e2]; v1 += b1[rowb + 2 * e2 + 1]; }
            outp[(size_t)((rowb >> 1) + e2) * ldc + colb] = packh2(v0, v1);
        }
    }
}

// ---------------------------------------------------------------------------
// out[n,m] = b2 + sum_{h2=0..255} relu(hx_pair + cm_pair) . w2_pair
// Direct output, no h-split: tile 64n x 32m, grid 32x8 = 256 blocks, KC=64 h2
// chunks (4), double-buffered LDS with register prefetch. Strides LDH=72 /
// LDC=40 keep all LDS ops <=2-way bank aliasing (free).
// ---------------------------------------------------------------------------
__global__ __launch_bounds__(256, 2)
void fused_out(const unsigned int* __restrict__ hxT_p,   // [256][2048]
               const unsigned int* __restrict__ cmT_p,   // [256][256]
               const float* __restrict__ w2,
               const float* __restrict__ b2,
               float* __restrict__ out)
{
    constexpr int TN = 64, TM = 32, KC = 64, NCH = 256 / KC;   // 4 chunks
    constexpr int LDH = 72, LDC = 40;
    __shared__ unsigned int Hs[2][KC][LDH];
    __shared__ unsigned int Cs[2][KC][LDC];
    __shared__ unsigned int Wsh[256];

    const int tid = threadIdx.x;
    const int tx = tid & 15, ty = tid >> 4;
    const int n0 = blockIdx.x * TN;
    const int m0 = blockIdx.y * TM;

    // pack w2 into f16 h-pairs once (256 threads, one h2 each)
    Wsh[tid] = packh2(w2[2 * tid], w2[2 * tid + 1]);

    uint4 ph[4], pc[2];
    auto issue = [&](int kb) {
#pragma unroll
        for (int p = 0; p < 4; ++p) {
            const int idx = tid + p * 256, r = idx >> 4, c4 = idx & 15;
            ph[p] = *(const uint4*)&hxT_p[(size_t)(kb + r) * N_ + n0 + c4 * 4];
        }
#pragma unroll
        for (int p = 0; p < 2; ++p) {
            const int idx = tid + p * 256, r = idx >> 3, c4 = idx & 7;
            pc[p] = *(const uint4*)&cmT_p[(size_t)(kb + r) * M_ + m0 + c4 * 4];
        }
    };
    auto store = [&](int b) {
#pragma unroll
        for (int p = 0; p < 4; ++p) {
            const int idx = tid + p * 256, r = idx >> 4, c4 = idx & 15;
            *(uint4*)&Hs[b][r][c4 * 4] = ph[p];
        }
#pragma unroll
        for (int p = 0; p < 2; ++p) {
            const int idx = tid + p * 256, r = idx >> 3, c4 = idx & 7;
            *(uint4*)&Cs[b][r][c4 * 4] = pc[p];
        }
    };

    float acc[4][2];
#pragma unroll
    for (int i = 0; i < 4; ++i) { acc[i][0] = 0.f; acc[i][1] = 0.f; }

#ifndef HAVE_FDOT2
    U32H2 facc[4][2];
#pragma unroll
    for (int i = 0; i < 4; ++i) { facc[i][0].u = 0u; facc[i][1].u = 0u; }
#endif

    issue(0); store(0);
    for (int c = 0; c < NCH; ++c) {
        const int buf = c & 1;
        __syncthreads();
        if (c + 1 < NCH) issue((c + 1) * KC);
#pragma unroll 8
        for (int h = 0; h < KC; ++h) {
            const uint4 av = *(const uint4*)&Hs[buf][h][ty * 4];
            const uint2 bv = *(const uint2*)&Cs[buf][h][tx * 2];
            U32H2 w; w.u = Wsh[c * KC + h];
            U32H2 a[4], b[2];
            a[0].u = av.x; a[1].u = av.y; a[2].u = av.z; a[3].u = av.w;
            b[0].u = bv.x; b[1].u = bv.y;
#pragma unroll
            for (int i = 0; i < 4; ++i)
#pragma unroll
                for (int j = 0; j < 2; ++j) {
                    const h2v s = relu2(a[i].v + b[j].v);
#ifdef HAVE_FDOT2
                    acc[i][j] = __builtin_amdgcn_fdot2(s, w.v, acc[i][j], false);
#else
                    facc[i][j].v = s * w.v + facc[i][j].v;
#endif
                }
#ifndef HAVE_FDOT2
            if ((h & 7) == 7) {
#pragma unroll
                for (int i = 0; i < 4; ++i)
#pragma unroll
                    for (int j = 0; j < 2; ++j) {
                        acc[i][j] += (float)facc[i][j].v[0] + (float)facc[i][j].v[1];
                        facc[i][j].u = 0u;
                    }
            }
#endif
        }
        if (c + 1 < NCH) store((c + 1) & 1);
    }

    const float bb = b2[0];
#pragma unroll
    for (int i = 0; i < 4; ++i) {
        float2 o;
        o.x = acc[i][0] + bb;
        o.y = acc[i][1] + bb;
        *(float2*)&out[(size_t)(n0 + ty * 4 + i) * M_ + m0 + tx * 2] = o;
    }
}

// ---------------------------------------------------------------------------
extern "C" void kernel_launch(void* const* d_in, const int* in_sizes, int n_in,
                              void* d_out, int out_size, void* d_ws, size_t ws_size,
                              hipStream_t stream)
{
    const float* x      = (const float*)d_in[0];
    const int*   tuples = (const int*)d_in[1];
    const float* Wa     = (const float*)d_in[2];
    const float* ba     = (const float*)d_in[3];
    const float* Wb     = (const float*)d_in[4];
    const float* bb     = (const float*)d_in[5];
    const float* E_pred = (const float*)d_in[6];
    const float* E_filt = (const float*)d_in[7];
    const float* E_reo  = (const float*)d_in[8];
    const float* W1     = (const float*)d_in[9];
    const float* b1     = (const float*)d_in[10];
    const float* W2     = (const float*)d_in[11];
    const float* b2     = (const float*)d_in[12];
    float* out = (float*)d_out;

    // ws: disjoint regions
    char* w = (char*)d_ws;
    unsigned short* h_x_bf   = (unsigned short*)(w + (0 << 20));    // 2 MB
    unsigned short* x_emb_bf = (unsigned short*)(w + (4 << 20));    // 1 MB
    unsigned int*   hxT_p    = (unsigned int*)(w + (8 << 20));      // 2 MB
    unsigned int*   cmT_p    = (unsigned int*)(w + (12 << 20));     // 256 KB

    // h_x = relu(x @ Wa^T + ba)   (2048x512, K=512), converts x+Wa inline
    gemm_cvt<32, 64, true><<<dim3(N_ / 32, HID / 64), 256, 0, stream>>>(
        x, IN_DIM, Wa, IN_DIM, ba, h_x_bf, HID, IN_DIM);

    // x_emb = relu(h_x @ Wb^T + bb)  (2048x256, K=512), converts Wb inline
    gemm_cvt<32, 32, false><<<dim3(N_ / 32, EMB / 32), 256, 0, stream>>>(
        h_x_bf, HID, Wb, HID, bb, x_emb_bf, EMB, HID);

    // hxT_p[h2][n] & cmT_p[h2][m] (f16 h-pairs); W1 cvt + t_emb gather inline
    gemm_pair<<<dim3(HID / 32, 36), 256, 0, stream>>>(
        W1, x_emb_bf, tuples, E_pred, E_filt, E_reo, b1, hxT_p, cmT_p);

    // out[n,m] = b2 + sum_h relu(hxT + cmT) . w2   (direct, no partials)
    fused_out<<<dim3(N_ / 64, M_ / 32), 256, 0, stream>>>(
        hxT_p, cmT_p, W2, b2, out);
}